// Round 2
// baseline (637.202 us; speedup 1.0000x reference)
//
#include <hip/hip_runtime.h>
#include <hip/hip_bf16.h>
#include <stdint.h>

#define BN_EPS 1e-5f

static __device__ __forceinline__ float bflo2f(uint32_t p){
  union { uint32_t u; float f; } c; c.u = p << 16; return c.f;
}
static __device__ __forceinline__ float bfhi2f(uint32_t p){
  union { uint32_t u; float f; } c; c.u = p & 0xffff0000u; return c.f;
}
static __device__ __forceinline__ uint16_t f2bf(float f){
  union { float f; uint32_t u; } c; c.f = f;
  uint32_t u = c.u;
  return (uint16_t)((u + 0x7fffu + ((u >> 16) & 1u)) >> 16);
}

// ---------------- CSR build ----------------
__global__ void k_hist(const int* __restrict__ dst, int* __restrict__ deg, int E){
  int i = blockIdx.x * 256 + threadIdx.x;
  if (i < E) atomicAdd(&deg[dst[i]], 1);
}

__global__ void k_scan1(const int* __restrict__ deg, int* __restrict__ bsums, int n){
  __shared__ int red[256];
  int base = blockIdx.x * 1024;
  int s = 0;
  for (int j = threadIdx.x; j < 1024; j += 256){
    int i = base + j;
    if (i < n) s += deg[i];
  }
  red[threadIdx.x] = s;
  __syncthreads();
  for (int off = 128; off > 0; off >>= 1){
    if (threadIdx.x < off) red[threadIdx.x] += red[threadIdx.x + off];
    __syncthreads();
  }
  if (threadIdx.x == 0) bsums[blockIdx.x] = red[0];
}

__global__ void k_scan2(int* __restrict__ bsums, int nb, int* __restrict__ row_off, int n, int E){
  if (blockIdx.x == 0 && threadIdx.x == 0){
    int acc = 0;
    for (int b = 0; b < nb; ++b){ int t = bsums[b]; bsums[b] = acc; acc += t; }
    row_off[n] = E;
  }
}

__global__ void k_scan3(const int* __restrict__ deg, const int* __restrict__ bsums,
                        int* __restrict__ row_off, int n){
  __shared__ int sc[256];
  int t = threadIdx.x;
  int base = blockIdx.x * 1024 + t * 4;
  int v0 = (base + 0 < n) ? deg[base + 0] : 0;
  int v1 = (base + 1 < n) ? deg[base + 1] : 0;
  int v2 = (base + 2 < n) ? deg[base + 2] : 0;
  int v3 = (base + 3 < n) ? deg[base + 3] : 0;
  int tsum = v0 + v1 + v2 + v3;
  sc[t] = tsum;
  __syncthreads();
  for (int off = 1; off < 256; off <<= 1){
    int add = (t >= off) ? sc[t - off] : 0;
    __syncthreads();
    sc[t] += add;
    __syncthreads();
  }
  int exc = sc[t] - tsum + bsums[blockIdx.x];
  if (base + 0 < n) row_off[base + 0] = exc;
  if (base + 1 < n) row_off[base + 1] = exc + v0;
  if (base + 2 < n) row_off[base + 2] = exc + v0 + v1;
  if (base + 3 < n) row_off[base + 3] = exc + v0 + v1 + v2;
}

__global__ void k_fill(const int* __restrict__ src, const int* __restrict__ dst,
                       const int* __restrict__ row_off, int* __restrict__ cursor,
                       int* __restrict__ col_idx, int E){
  int e = blockIdx.x * 256 + threadIdx.x;
  if (e < E){
    int d = dst[e];
    int p = row_off[d] + atomicAdd(&cursor[d], 1);
    col_idx[p] = src[e];
  }
}

// ---------------- gather: pooled = sum_{src in N(dst)} h[src] + (1+eps)*h[dst] ----------------
__global__ void k_gather(const float* __restrict__ h, const int* __restrict__ row_off,
                         const int* __restrict__ col_idx, const float* __restrict__ eps_p,
                         float* __restrict__ X, int n){
  int node = (blockIdx.x << 2) + (threadIdx.x >> 6);
  int lane = threadIdx.x & 63;
  if (node >= n) return;
  const float2* hp = (const float2*)h;   // 2 floats per lane
  float2 vh = hp[(size_t)node * 64 + lane];
  int j = row_off[node], jend = row_off[node + 1];
  float a0 = 0.f, a1 = 0.f;
  for (; j + 1 < jend; j += 2){
    int sA = col_idx[j], sB = col_idx[j + 1];
    float2 vA = hp[(size_t)sA * 64 + lane];
    float2 vB = hp[(size_t)sB * 64 + lane];
    a0 += vA.x + vB.x;
    a1 += vA.y + vB.y;
  }
  if (j < jend){
    float2 vA = hp[(size_t)col_idx[j] * 64 + lane];
    a0 += vA.x;
    a1 += vA.y;
  }
  float ce = 1.0f + eps_p[0];
  a0 += ce * vh.x;
  a1 += ce * vh.y;
  float2 st; st.x = a0; st.y = a1;
  *(float2*)(X + (size_t)node * 128 + lane * 2) = st;
}

// ---------------- GEMM (in-place, fused BN-in + relu on staging, fused column stats out) ----------------
// W is staged into LDS as bf16 (fp32->bf16 at staging). BN on the next layer
// cancels per-column scale error; residual rounding noise ~0.3% << 2% tol.
template<bool BN_IN>
__global__ __launch_bounds__(256, 2) void k_gemm(float* __restrict__ Xio,
    const float* __restrict__ Wf, const float* __restrict__ bias_f,
    const float* __restrict__ ABin,
    float* __restrict__ osum, float* __restrict__ osq, int n){
  __shared__ __align__(16) uint16_t Wl[128 * 128];   // 32 KB bf16
  __shared__ __align__(16) float Al[64 * 132];       // 33.8 KB fp32, padded stride
  __shared__ float csum[128], csq[128];
  int tid = threadIdx.x;
  int rbase = blockIdx.x * 64;

  { // stage W: fp32 -> bf16
    uint32_t* Wd = (uint32_t*)Wl;   // 2 bf16 per uint32
    #pragma unroll
    for (int i = 0; i < 16; ++i){
      int f4 = tid + 256 * i;       // float4 index, 4096 total
      float4 w = *(const float4*)(Wf + f4 * 4);
      uint32_t lo = (uint32_t)f2bf(w.x) | ((uint32_t)f2bf(w.y) << 16);
      uint32_t hi = (uint32_t)f2bf(w.z) | ((uint32_t)f2bf(w.w) << 16);
      Wd[f4 * 2]     = lo;
      Wd[f4 * 2 + 1] = hi;
    }
  }
  // stage A tile (optionally BN+relu transform)
  #pragma unroll
  for (int i = 0; i < 8; ++i){
    int f4 = tid + 256 * i;
    int flat = f4 * 4;
    int r = flat >> 7, k = flat & 127;
    int gr = rbase + r;
    float4 v = make_float4(0.f, 0.f, 0.f, 0.f);
    if (gr < n) v = *(const float4*)(Xio + (size_t)gr * 128 + k);
    if (BN_IN){
      float4 sa = *(const float4*)(ABin + k);
      float4 sb = *(const float4*)(ABin + 128 + k);
      v.x = fmaxf(fmaf(v.x, sa.x, sb.x), 0.f);
      v.y = fmaxf(fmaf(v.y, sa.y, sb.y), 0.f);
      v.z = fmaxf(fmaf(v.z, sa.z, sb.z), 0.f);
      v.w = fmaxf(fmaf(v.w, sa.w, sb.w), 0.f);
    }
    *(float4*)(Al + r * 132 + k) = v;
  }
  if (tid < 128){ csum[tid] = 0.f; csq[tid] = 0.f; }
  __syncthreads();

  int c0 = (tid & 15) * 8;
  int r0 = (tid >> 4) * 4;
  float acc[4][8];
  #pragma unroll
  for (int rr = 0; rr < 4; ++rr)
    #pragma unroll
    for (int cc = 0; cc < 8; ++cc) acc[rr][cc] = 0.f;

  const float* A0 = Al + r0 * 132;
  #pragma unroll 2
  for (int k = 0; k < 128; ++k){
    uint4 wp = *(const uint4*)(Wl + (k << 7) + c0);
    float w[8];
    w[0] = bflo2f(wp.x); w[1] = bfhi2f(wp.x);
    w[2] = bflo2f(wp.y); w[3] = bfhi2f(wp.y);
    w[4] = bflo2f(wp.z); w[5] = bfhi2f(wp.z);
    w[6] = bflo2f(wp.w); w[7] = bfhi2f(wp.w);
    #pragma unroll
    for (int rr = 0; rr < 4; ++rr){
      float a = A0[rr * 132 + k];
      #pragma unroll
      for (int cc = 0; cc < 8; ++cc) acc[rr][cc] = fmaf(a, w[cc], acc[rr][cc]);
    }
  }

  float bias[8];
  #pragma unroll
  for (int cc = 0; cc < 8; ++cc) bias[cc] = bias_f[c0 + cc];

  float psum[8], psq[8];
  #pragma unroll
  for (int cc = 0; cc < 8; ++cc){ psum[cc] = 0.f; psq[cc] = 0.f; }

  #pragma unroll
  for (int rr = 0; rr < 4; ++rr){
    int gr = rbase + r0 + rr;
    if (gr < n){
      float y[8];
      #pragma unroll
      for (int cc = 0; cc < 8; ++cc){
        y[cc] = acc[rr][cc] + bias[cc];
        psum[cc] += y[cc];
        psq[cc] += y[cc] * y[cc];
      }
      float4 s0; s0.x=y[0]; s0.y=y[1]; s0.z=y[2]; s0.w=y[3];
      float4 s1; s1.x=y[4]; s1.y=y[5]; s1.z=y[6]; s1.w=y[7];
      *(float4*)(Xio + (size_t)gr * 128 + c0) = s0;
      *(float4*)(Xio + (size_t)gr * 128 + c0 + 4) = s1;
    }
  }
  #pragma unroll
  for (int cc = 0; cc < 8; ++cc){
    atomicAdd(&csum[c0 + cc], psum[cc]);
    atomicAdd(&csq[c0 + cc], psq[cc]);
  }
  __syncthreads();
  if (tid < 128){
    atomicAdd(&osum[tid], csum[tid]);
    atomicAdd(&osq[tid], csq[tid]);
  }
}

__global__ void k_bncoef(const float* __restrict__ sum, const float* __restrict__ sq,
                         const float* __restrict__ g, const float* __restrict__ be,
                         float* __restrict__ AB, float invN){
  int c = threadIdx.x;
  if (c < 128){
    float mu = sum[c] * invN;
    float var = sq[c] * invN - mu * mu;
    float A = g[c] * rsqrtf(var + BN_EPS);
    float B = be[c] - mu * A;
    AB[c] = A;
    AB[128 + c] = B;
  }
}

__global__ void k_final(const float* __restrict__ X, const float* __restrict__ AB,
                        float* __restrict__ out, int total){
  int i = (blockIdx.x * 256 + threadIdx.x) * 4;
  if (i >= total) return;
  float4 v = *(const float4*)(X + i);
  int c = i & 127;
  float4 a = *(const float4*)(AB + c);
  float4 b = *(const float4*)(AB + 128 + c);
  float4 o;
  o.x = fmaxf(fmaf(v.x, a.x, b.x), 0.f);
  o.y = fmaxf(fmaf(v.y, a.y, b.y), 0.f);
  o.z = fmaxf(fmaf(v.z, a.z, b.z), 0.f);
  o.w = fmaxf(fmaf(v.w, a.w, b.w), 0.f);
  *(float4*)(out + i) = o;
}

extern "C" void kernel_launch(void* const* d_in, const int* in_sizes, int n_in,
                              void* d_out, int out_size, void* d_ws, size_t ws_size,
                              hipStream_t stream){
  const float* h    = (const float*)d_in[0];
  const int*   esrc = (const int*)d_in[1];
  const int*   edst = (const int*)d_in[2];
  const float* W1   = (const float*)d_in[3];
  const float* b1   = (const float*)d_in[4];
  const float* g1   = (const float*)d_in[5];
  const float* be1  = (const float*)d_in[6];
  const float* W2   = (const float*)d_in[7];
  const float* b2   = (const float*)d_in[8];
  const float* g2   = (const float*)d_in[9];
  const float* be2  = (const float*)d_in[10];
  const float* eps  = (const float*)d_in[11];
  int n = in_sizes[0] / 128;
  int E = in_sizes[1];
  (void)n_in; (void)out_size; (void)ws_size;

  char* ws = (char*)d_ws;
  size_t off = 0;
  auto alloc = [&](size_t bytes) -> void* {
    void* p = ws + off;
    off += (bytes + 511) & ~(size_t)511;
    return p;
  };
  float* X       = (float*)alloc((size_t)n * 128 * 4);   // pooled -> y1 -> y2 (in-place)
  int*   deg     = (int*)alloc((size_t)n * 4);
  int*   row_off = (int*)alloc((size_t)(n + 1) * 4);
  int*   cursor  = (int*)alloc((size_t)n * 4);
  int*   col_idx = (int*)alloc((size_t)E * 4);
  int*   bsums   = (int*)alloc(1024 * 4);
  float* stats   = (float*)alloc(512 * 4);
  float* AB1     = (float*)alloc(256 * 4);
  float* AB2     = (float*)alloc(256 * 4);
  float* sum1 = stats;        float* sq1 = stats + 128;
  float* sum2 = stats + 256;  float* sq2 = stats + 384;

  hipMemsetAsync(deg, 0, (size_t)n * 4, stream);
  hipMemsetAsync(cursor, 0, (size_t)n * 4, stream);
  hipMemsetAsync(stats, 0, 512 * 4, stream);

  int nb = (n + 1023) / 1024;
  k_hist <<<(E + 255) / 256, 256, 0, stream>>>(edst, deg, E);
  k_scan1<<<nb, 256, 0, stream>>>(deg, bsums, n);
  k_scan2<<<1, 64, 0, stream>>>(bsums, nb, row_off, n, E);
  k_scan3<<<nb, 256, 0, stream>>>(deg, bsums, row_off, n);
  k_fill <<<(E + 255) / 256, 256, 0, stream>>>(esrc, edst, row_off, cursor, col_idx, E);
  k_gather<<<(n + 3) / 4, 256, 0, stream>>>(h, row_off, col_idx, eps, X, n);

  int gblocks = (n + 63) / 64;
  k_gemm<false><<<gblocks, 256, 0, stream>>>(X, W1, b1, nullptr, sum1, sq1, n);
  k_bncoef<<<1, 128, 0, stream>>>(sum1, sq1, g1, be1, AB1, 1.0f / (float)n);
  k_gemm<true> <<<gblocks, 256, 0, stream>>>(X, W2, b2, AB1, sum2, sq2, n);
  k_bncoef<<<1, 128, 0, stream>>>(sum2, sq2, g2, be2, AB2, 1.0f / (float)n);

  int total = n * 128;
  k_final<<<(total / 4 + 255) / 256, 256, 0, stream>>>(X, AB2, (float*)d_out, total);
}

// Round 3
// 486.991 us; speedup vs baseline: 1.3084x; 1.3084x over previous
//
#include <hip/hip_runtime.h>
#include <hip/hip_bf16.h>
#include <stdint.h>

#define BN_EPS 1e-5f

typedef __attribute__((ext_vector_type(8)))  short bf16x8;   // 8 bf16 = 4 VGPRs
typedef __attribute__((ext_vector_type(16))) float f32x16;   // 32x32 MFMA acc

static __device__ __forceinline__ float bflo2f(uint32_t p){
  union { uint32_t u; float f; } c; c.u = p << 16; return c.f;
}
static __device__ __forceinline__ float bfhi2f(uint32_t p){
  union { uint32_t u; float f; } c; c.u = p & 0xffff0000u; return c.f;
}
static __device__ __forceinline__ uint16_t f2bf(float f){
  union { float f; uint32_t u; } c; c.f = f;
  uint32_t u = c.u;
  return (uint16_t)((u + 0x7fffu + ((u >> 16) & 1u)) >> 16);
}
static __device__ __forceinline__ uint32_t pack2(float a, float b){
  return (uint32_t)f2bf(a) | ((uint32_t)f2bf(b) << 16);
}

// ---------------- prepasses ----------------
// h fp32 -> bf16 (halves gather traffic)
__global__ void k_prep_h(const float* __restrict__ h, uint16_t* __restrict__ hb, int total8){
  int t = blockIdx.x * 256 + threadIdx.x;
  if (t >= total8) return;
  int i = t * 8;
  float4 a = *(const float4*)(h + i);
  float4 b = *(const float4*)(h + i + 4);
  uint4 o;
  o.x = pack2(a.x, a.y); o.y = pack2(a.z, a.w);
  o.z = pack2(b.x, b.y); o.w = pack2(b.z, b.w);
  *(uint4*)(hb + i) = o;
}

// W fp32 [k][n] -> Wt bf16 [n][k] with 16B-chunk XOR swizzle (chunk c -> c ^ (n&15))
__global__ void k_prep_w(const float* __restrict__ W1, const float* __restrict__ W2,
                         uint16_t* __restrict__ Wt1, uint16_t* __restrict__ Wt2){
  int gid = blockIdx.x * 256 + threadIdx.x;   // 4096 chunks total
  if (gid >= 4096) return;
  const float* Wf = (gid < 2048) ? W1 : W2;
  uint16_t* Wt = (gid < 2048) ? Wt1 : Wt2;
  int cid = gid & 2047;
  int nrow = cid >> 4;      // 0..127  (output col)
  int c    = cid & 15;      // k-chunk
  int k0 = c * 8;
  float e[8];
  #pragma unroll
  for (int j = 0; j < 8; ++j) e[j] = Wf[(k0 + j) * 128 + nrow];
  uint4 o;
  o.x = pack2(e[0], e[1]); o.y = pack2(e[2], e[3]);
  o.z = pack2(e[4], e[5]); o.w = pack2(e[6], e[7]);
  int cs = c ^ (nrow & 15);
  *(uint4*)(Wt + nrow * 128 + cs * 8) = o;
}

// ---------------- CSR build ----------------
__global__ void k_hist(const int* __restrict__ dst, int* __restrict__ deg, int E){
  int i = blockIdx.x * 256 + threadIdx.x;
  if (i < E) atomicAdd(&deg[dst[i]], 1);
}

__global__ void k_scan1(const int* __restrict__ deg, int* __restrict__ bsums, int n){
  __shared__ int red[256];
  int base = blockIdx.x * 1024;
  int s = 0;
  for (int j = threadIdx.x; j < 1024; j += 256){
    int i = base + j;
    if (i < n) s += deg[i];
  }
  red[threadIdx.x] = s;
  __syncthreads();
  for (int off = 128; off > 0; off >>= 1){
    if (threadIdx.x < off) red[threadIdx.x] += red[threadIdx.x + off];
    __syncthreads();
  }
  if (threadIdx.x == 0) bsums[blockIdx.x] = red[0];
}

__global__ void k_scan2(int* __restrict__ bsums, int nb, int* __restrict__ row_off, int n, int E){
  if (blockIdx.x == 0 && threadIdx.x == 0){
    int acc = 0;
    for (int b = 0; b < nb; ++b){ int t = bsums[b]; bsums[b] = acc; acc += t; }
    row_off[n] = E;
  }
}

__global__ void k_scan3(const int* __restrict__ deg, const int* __restrict__ bsums,
                        int* __restrict__ row_off, int n){
  __shared__ int sc[256];
  int t = threadIdx.x;
  int base = blockIdx.x * 1024 + t * 4;
  int v0 = (base + 0 < n) ? deg[base + 0] : 0;
  int v1 = (base + 1 < n) ? deg[base + 1] : 0;
  int v2 = (base + 2 < n) ? deg[base + 2] : 0;
  int v3 = (base + 3 < n) ? deg[base + 3] : 0;
  int tsum = v0 + v1 + v2 + v3;
  sc[t] = tsum;
  __syncthreads();
  for (int off = 1; off < 256; off <<= 1){
    int add = (t >= off) ? sc[t - off] : 0;
    __syncthreads();
    sc[t] += add;
    __syncthreads();
  }
  int exc = sc[t] - tsum + bsums[blockIdx.x];
  if (base + 0 < n) row_off[base + 0] = exc;
  if (base + 1 < n) row_off[base + 1] = exc + v0;
  if (base + 2 < n) row_off[base + 2] = exc + v0 + v1;
  if (base + 3 < n) row_off[base + 3] = exc + v0 + v1 + v2;
}

__global__ void k_fill(const int* __restrict__ src, const int* __restrict__ dst,
                       const int* __restrict__ row_off, int* __restrict__ cursor,
                       int* __restrict__ col_idx, int E){
  int e = blockIdx.x * 256 + threadIdx.x;
  if (e < E){
    int d = dst[e];
    int p = row_off[d] + atomicAdd(&cursor[d], 1);
    col_idx[p] = src[e];
  }
}

// -------- gather: pooled = sum_{src in N(dst)} h[src] + (1+eps)*h[dst]  (bf16 in, bf16 out) --------
__global__ void k_gather(const uint16_t* __restrict__ hb, const int* __restrict__ row_off,
                         const int* __restrict__ col_idx, const float* __restrict__ eps_p,
                         uint16_t* __restrict__ Xb, int n){
  int node = (blockIdx.x << 2) + (threadIdx.x >> 6);
  int lane = threadIdx.x & 63;
  if (node >= n) return;
  const uint32_t* hp = (const uint32_t*)hb;  // 2 bf16 per uint
  uint32_t vh = hp[(size_t)node * 64 + lane];
  int j = row_off[node], jend = row_off[node + 1];
  float a0 = 0.f, a1 = 0.f;
  for (; j + 3 < jend; j += 4){
    int s0 = col_idx[j], s1 = col_idx[j + 1], s2 = col_idx[j + 2], s3 = col_idx[j + 3];
    uint32_t v0 = hp[(size_t)s0 * 64 + lane];
    uint32_t v1 = hp[(size_t)s1 * 64 + lane];
    uint32_t v2 = hp[(size_t)s2 * 64 + lane];
    uint32_t v3 = hp[(size_t)s3 * 64 + lane];
    a0 += (bflo2f(v0) + bflo2f(v1)) + (bflo2f(v2) + bflo2f(v3));
    a1 += (bfhi2f(v0) + bfhi2f(v1)) + (bfhi2f(v2) + bfhi2f(v3));
  }
  for (; j < jend; ++j){
    uint32_t v = hp[(size_t)col_idx[j] * 64 + lane];
    a0 += bflo2f(v);
    a1 += bfhi2f(v);
  }
  float ce = 1.0f + eps_p[0];
  a0 += ce * bflo2f(vh);
  a1 += ce * bfhi2f(vh);
  ((uint32_t*)Xb)[(size_t)node * 64 + lane] = pack2(a0, a1);
}

// -------- MFMA GEMM: Y[64rows x 128] = A[64x128] @ W[128x128] + bias, optional BN+ReLU on input,
//          bf16 output, fused column sum/sumsq (fp32 acc) for the NEXT BN --------
template<bool BN_IN>
__global__ __launch_bounds__(256, 3) void k_mgemm(
    const uint16_t* __restrict__ Ag, const uint16_t* __restrict__ Wt,
    const float* __restrict__ bias_f, const float* __restrict__ ABin,
    uint16_t* __restrict__ Yout, float* __restrict__ osum, float* __restrict__ osq, int n){
  __shared__ __align__(16) uint16_t Al[64 * 128];    // 16 KB, XOR-swizzled 16B chunks
  __shared__ __align__(16) uint16_t Wl[128 * 128];   // 32 KB, pre-swizzled in global
  __shared__ float csum[128], csq[128];
  int tid = threadIdx.x;
  int rbase = blockIdx.x * 64;

  // stage W: straight 32 KB copy (swizzle already baked in)
  {
    const uint4* g = (const uint4*)Wt;
    uint4* d = (uint4*)Wl;
    #pragma unroll
    for (int i = 0; i < 8; ++i) d[tid + 256 * i] = g[tid + 256 * i];
  }
  // stage A: 1024 chunks of 16B, swizzle on write; optional BN+ReLU transform
  #pragma unroll
  for (int i = 0; i < 4; ++i){
    int f = tid + 256 * i;
    int m = f >> 4, c = f & 15;
    int gr = rbase + m;
    uint4 v = make_uint4(0, 0, 0, 0);
    if (gr < n){
      v = *(const uint4*)(Ag + (size_t)gr * 128 + c * 8);
      if (BN_IN){
        int k0 = c * 8;
        float4 ka0 = *(const float4*)(ABin + k0);
        float4 ka1 = *(const float4*)(ABin + k0 + 4);
        float4 kb0 = *(const float4*)(ABin + 128 + k0);
        float4 kb1 = *(const float4*)(ABin + 128 + k0 + 4);
        float e0 = fmaxf(fmaf(bflo2f(v.x), ka0.x, kb0.x), 0.f);
        float e1 = fmaxf(fmaf(bfhi2f(v.x), ka0.y, kb0.y), 0.f);
        float e2 = fmaxf(fmaf(bflo2f(v.y), ka0.z, kb0.z), 0.f);
        float e3 = fmaxf(fmaf(bfhi2f(v.y), ka0.w, kb0.w), 0.f);
        float e4 = fmaxf(fmaf(bflo2f(v.z), ka1.x, kb1.x), 0.f);
        float e5 = fmaxf(fmaf(bfhi2f(v.z), ka1.y, kb1.y), 0.f);
        float e6 = fmaxf(fmaf(bflo2f(v.w), ka1.z, kb1.z), 0.f);
        float e7 = fmaxf(fmaf(bfhi2f(v.w), ka1.w, kb1.w), 0.f);
        v.x = pack2(e0, e1); v.y = pack2(e2, e3);
        v.z = pack2(e4, e5); v.w = pack2(e6, e7);
      }
    }
    *(uint4*)((char*)Al + m * 256 + ((c ^ (m & 15)) * 16)) = v;
  }
  if (tid < 128){ csum[tid] = 0.f; csq[tid] = 0.f; }
  __syncthreads();

  int lane = tid & 63;
  int w    = tid >> 6;
  int hi   = lane >> 5;          // k-half selector
  int key  = lane & 15;          // swizzle key (same for A and W rows)
  int m0   = (w & 1) * 32;
  int n0   = (w >> 1) * 64;
  int mrow = m0 + (lane & 31);
  int nrow0 = n0 + (lane & 31);
  int nrow1 = nrow0 + 32;

  f32x16 acc0, acc1;
  #pragma unroll
  for (int i = 0; i < 16; ++i){ acc0[i] = 0.f; acc1[i] = 0.f; }

  const char* Ab = (const char*)Al;
  const char* Wb = (const char*)Wl;
  #pragma unroll
  for (int kt = 0; kt < 8; ++kt){
    int cs = ((2 * kt + hi) ^ key) * 16;
    bf16x8 a  = *(const bf16x8*)(Ab + mrow  * 256 + cs);
    bf16x8 b0 = *(const bf16x8*)(Wb + nrow0 * 256 + cs);
    bf16x8 b1 = *(const bf16x8*)(Wb + nrow1 * 256 + cs);
    acc0 = __builtin_amdgcn_mfma_f32_32x32x16_bf16(a, b0, acc0, 0, 0, 0);
    acc1 = __builtin_amdgcn_mfma_f32_32x32x16_bf16(a, b1, acc1, 0, 0, 0);
  }

  // epilogue: C/D layout col=lane&31, row=(reg&3)+8*(reg>>2)+4*(lane>>5)
  float bias0 = bias_f[nrow0];
  float bias1 = bias_f[nrow1];
  float ps0 = 0.f, pq0 = 0.f, ps1 = 0.f, pq1 = 0.f;
  #pragma unroll
  for (int r = 0; r < 16; ++r){
    int row = (r & 3) + 8 * (r >> 2) + 4 * hi;
    int gr = rbase + m0 + row;
    if (gr < n){
      float y0 = acc0[r] + bias0;
      float y1 = acc1[r] + bias1;
      ps0 += y0; pq0 += y0 * y0;
      ps1 += y1; pq1 += y1 * y1;
      Yout[(size_t)gr * 128 + nrow0] = f2bf(y0);
      Yout[(size_t)gr * 128 + nrow1] = f2bf(y1);
    }
  }
  atomicAdd(&csum[nrow0], ps0); atomicAdd(&csq[nrow0], pq0);
  atomicAdd(&csum[nrow1], ps1); atomicAdd(&csq[nrow1], pq1);
  __syncthreads();
  if (tid < 128){
    atomicAdd(&osum[tid], csum[tid]);
    atomicAdd(&osq[tid], csq[tid]);
  }
}

__global__ void k_bncoef(const float* __restrict__ sum, const float* __restrict__ sq,
                         const float* __restrict__ g, const float* __restrict__ be,
                         float* __restrict__ AB, float invN){
  int c = threadIdx.x;
  if (c < 128){
    float mu = sum[c] * invN;
    float var = sq[c] * invN - mu * mu;
    float A = g[c] * rsqrtf(var + BN_EPS);
    float B = be[c] - mu * A;
    AB[c] = A;
    AB[128 + c] = B;
  }
}

__global__ void k_final(const uint16_t* __restrict__ Y2b, const float* __restrict__ AB,
                        float* __restrict__ out, int total){
  int i = (blockIdx.x * 256 + threadIdx.x) * 4;
  if (i >= total) return;
  uint2 v = *(const uint2*)(Y2b + i);
  int c = i & 127;
  float4 a = *(const float4*)(AB + c);
  float4 b = *(const float4*)(AB + 128 + c);
  float4 o;
  o.x = fmaxf(fmaf(bflo2f(v.x), a.x, b.x), 0.f);
  o.y = fmaxf(fmaf(bfhi2f(v.x), a.y, b.y), 0.f);
  o.z = fmaxf(fmaf(bflo2f(v.y), a.z, b.z), 0.f);
  o.w = fmaxf(fmaf(bfhi2f(v.y), a.w, b.w), 0.f);
  *(float4*)(out + i) = o;
}

extern "C" void kernel_launch(void* const* d_in, const int* in_sizes, int n_in,
                              void* d_out, int out_size, void* d_ws, size_t ws_size,
                              hipStream_t stream){
  const float* h    = (const float*)d_in[0];
  const int*   esrc = (const int*)d_in[1];
  const int*   edst = (const int*)d_in[2];
  const float* W1   = (const float*)d_in[3];
  const float* b1   = (const float*)d_in[4];
  const float* g1   = (const float*)d_in[5];
  const float* be1  = (const float*)d_in[6];
  const float* W2   = (const float*)d_in[7];
  const float* b2   = (const float*)d_in[8];
  const float* g2   = (const float*)d_in[9];
  const float* be2  = (const float*)d_in[10];
  const float* eps  = (const float*)d_in[11];
  int n = in_sizes[0] / 128;
  int E = in_sizes[1];
  (void)n_in; (void)out_size; (void)ws_size;

  char* ws = (char*)d_ws;
  size_t off = 0;
  auto alloc = [&](size_t bytes) -> void* {
    void* p = ws + off;
    off += (bytes + 511) & ~(size_t)511;
    return p;
  };
  size_t feat_b = (size_t)n * 128 * 2;            // bf16 feature plane: 25.6 MB
  uint16_t* B1   = (uint16_t*)alloc(feat_b);       // hb  -> Y1b (aliased: hb dead after gather)
  uint16_t* B2   = (uint16_t*)alloc(feat_b);       // Xb  -> Y2b (aliased: Xb dead after gemm1)
  int*   deg     = (int*)alloc((size_t)n * 4);
  int*   row_off = (int*)alloc((size_t)(n + 1) * 4);
  int*   cursor  = (int*)alloc((size_t)n * 4);
  int*   col_idx = (int*)alloc((size_t)E * 4);
  int*   bsums   = (int*)alloc(1024 * 4);
  float* stats   = (float*)alloc(512 * 4);
  float* AB1     = (float*)alloc(256 * 4);
  float* AB2     = (float*)alloc(256 * 4);
  uint16_t* Wt1  = (uint16_t*)alloc(128 * 128 * 2);
  uint16_t* Wt2  = (uint16_t*)alloc(128 * 128 * 2);
  float* sum1 = stats;        float* sq1 = stats + 128;
  float* sum2 = stats + 256;  float* sq2 = stats + 384;
  uint16_t* hb  = B1;   // h bf16 (prepass -> gather)
  uint16_t* Xb  = B2;   // pooled bf16 (gather -> gemm1)
  uint16_t* Y1b = B1;   // y1 bf16 (gemm1 -> gemm2)
  uint16_t* Y2b = B2;   // y2 bf16 (gemm2 -> final)

  hipMemsetAsync(deg, 0, (size_t)n * 4, stream);
  hipMemsetAsync(cursor, 0, (size_t)n * 4, stream);
  hipMemsetAsync(stats, 0, 512 * 4, stream);

  int nb = (n + 1023) / 1024;
  int total = n * 128;
  k_prep_h<<<(total / 8 + 255) / 256, 256, 0, stream>>>(h, hb, total / 8);
  k_prep_w<<<16, 256, 0, stream>>>(W1, W2, Wt1, Wt2);
  k_hist <<<(E + 255) / 256, 256, 0, stream>>>(edst, deg, E);
  k_scan1<<<nb, 256, 0, stream>>>(deg, bsums, n);
  k_scan2<<<1, 64, 0, stream>>>(bsums, nb, row_off, n, E);
  k_scan3<<<nb, 256, 0, stream>>>(deg, bsums, row_off, n);
  k_fill <<<(E + 255) / 256, 256, 0, stream>>>(esrc, edst, row_off, cursor, col_idx, E);
  k_gather<<<(n + 3) / 4, 256, 0, stream>>>(hb, row_off, col_idx, eps, Xb, n);

  int gblocks = (n + 63) / 64;
  k_mgemm<false><<<gblocks, 256, 0, stream>>>(Xb, Wt1, b1, nullptr, Y1b, sum1, sq1, n);
  k_bncoef<<<1, 128, 0, stream>>>(sum1, sq1, g1, be1, AB1, 1.0f / (float)n);
  k_mgemm<true> <<<gblocks, 256, 0, stream>>>(Y1b, Wt2, b2, AB1, Y2b, sum2, sq2, n);
  k_bncoef<<<1, 128, 0, stream>>>(sum2, sq2, g2, be2, AB2, 1.0f / (float)n);

  k_final<<<(total / 4 + 255) / 256, 256, 0, stream>>>(Y2b, AB2, (float*)d_out, total);
}

// Round 4
// 383.842 us; speedup vs baseline: 1.6601x; 1.2687x over previous
//
#include <hip/hip_runtime.h>
#include <hip/hip_bf16.h>
#include <stdint.h>

#define BN_EPS 1e-5f

typedef __attribute__((ext_vector_type(8)))  short bf16x8;   // 8 bf16 = 4 VGPRs
typedef __attribute__((ext_vector_type(16))) float f32x16;   // 32x32 MFMA acc

static __device__ __forceinline__ float bflo2f(uint32_t p){
  union { uint32_t u; float f; } c; c.u = p << 16; return c.f;
}
static __device__ __forceinline__ float bfhi2f(uint32_t p){
  union { uint32_t u; float f; } c; c.u = p & 0xffff0000u; return c.f;
}
static __device__ __forceinline__ uint16_t f2bf(float f){
  union { float f; uint32_t u; } c; c.f = f;
  uint32_t u = c.u;
  return (uint16_t)((u + 0x7fffu + ((u >> 16) & 1u)) >> 16);
}
static __device__ __forceinline__ uint32_t pack2(float a, float b){
  return (uint32_t)f2bf(a) | ((uint32_t)f2bf(b) << 16);
}

// ---------------- prepasses ----------------
__global__ void k_prep_h(const float* __restrict__ h, uint16_t* __restrict__ hb, int total8){
  int t = blockIdx.x * 256 + threadIdx.x;
  if (t >= total8) return;
  int i = t * 8;
  float4 a = *(const float4*)(h + i);
  float4 b = *(const float4*)(h + i + 4);
  uint4 o;
  o.x = pack2(a.x, a.y); o.y = pack2(a.z, a.w);
  o.z = pack2(b.x, b.y); o.w = pack2(b.z, b.w);
  *(uint4*)(hb + i) = o;
}

// W fp32 [k][n] -> Wt bf16 [n][k] with 16B-chunk XOR swizzle (chunk c -> c ^ (n&15))
__global__ void k_prep_w(const float* __restrict__ W1, const float* __restrict__ W2,
                         uint16_t* __restrict__ Wt1, uint16_t* __restrict__ Wt2){
  int gid = blockIdx.x * 256 + threadIdx.x;   // 4096 chunks total
  if (gid >= 4096) return;
  const float* Wf = (gid < 2048) ? W1 : W2;
  uint16_t* Wt = (gid < 2048) ? Wt1 : Wt2;
  int cid = gid & 2047;
  int nrow = cid >> 4;
  int c    = cid & 15;
  int k0 = c * 8;
  float e[8];
  #pragma unroll
  for (int j = 0; j < 8; ++j) e[j] = Wf[(k0 + j) * 128 + nrow];
  uint4 o;
  o.x = pack2(e[0], e[1]); o.y = pack2(e[2], e[3]);
  o.z = pack2(e[4], e[5]); o.w = pack2(e[6], e[7]);
  int cs = c ^ (nrow & 15);
  *(uint4*)(Wt + nrow * 128 + cs * 8) = o;
}

// ---------------- binned CSR build (no global atomics) ----------------
// bucket = dst >> 8 (256 dst nodes per bucket). EB blocks of 4096 edges.
__global__ void k_bhist(const int* __restrict__ dst, int* __restrict__ M, int E, int NB){
  __shared__ int cnt[512];
  int t = threadIdx.x;
  cnt[t] = 0; cnt[t + 256] = 0;
  __syncthreads();
  int base = blockIdx.x * 4096;
  #pragma unroll 4
  for (int j = t; j < 4096; j += 256){
    int i = base + j;
    if (i < E) atomicAdd(&cnt[dst[i] >> 8], 1);
  }
  __syncthreads();
  size_t row = (size_t)blockIdx.x * NB;
  if (t < NB) M[row + t] = cnt[t];
  int t2 = t + 256;
  if (t2 < NB) M[row + t2] = cnt[t2];
}

// per-bucket column: exclusive scan over blocks (in place), total -> btot
__global__ void k_colscan(int* __restrict__ M, int* __restrict__ btot, int EB, int NB){
  __shared__ int s[256];
  int b = blockIdx.x, t = threadIdx.x;
  int i0 = 2 * t, i1 = 2 * t + 1;
  int v0 = (i0 < EB) ? M[(size_t)i0 * NB + b] : 0;
  int v1 = (i1 < EB) ? M[(size_t)i1 * NB + b] : 0;
  s[t] = v0 + v1;
  __syncthreads();
  for (int off = 1; off < 256; off <<= 1){
    int v = (t >= off) ? s[t - off] : 0;
    __syncthreads();
    s[t] += v;
    __syncthreads();
  }
  int excl = s[t] - (v0 + v1);
  if (i0 < EB) M[(size_t)i0 * NB + b] = excl;
  if (i1 < EB) M[(size_t)i1 * NB + b] = excl + v0;
  if (t == 255) btot[b] = s[255];
}

__global__ void k_bscan(const int* __restrict__ btot, int* __restrict__ bbase,
                        int* __restrict__ row_off, int NB, int n, int E){
  __shared__ int s[256];
  int t = threadIdx.x;
  int i0 = 2 * t, i1 = 2 * t + 1;
  int v0 = (i0 < NB) ? btot[i0] : 0;
  int v1 = (i1 < NB) ? btot[i1] : 0;
  s[t] = v0 + v1;
  __syncthreads();
  for (int off = 1; off < 256; off <<= 1){
    int v = (t >= off) ? s[t - off] : 0;
    __syncthreads();
    s[t] += v;
    __syncthreads();
  }
  int excl = s[t] - (v0 + v1);
  if (i0 < NB) bbase[i0] = excl;
  if (i1 < NB) bbase[i1] = excl + v0;
  if (t == 0){ bbase[NB] = E; row_off[n] = E; }
}

// scatter (src,dst) pairs into bucket-sorted array; deterministic placement
__global__ void k_bin(const int* __restrict__ src, const int* __restrict__ dst,
                      const int* __restrict__ M, const int* __restrict__ bbase,
                      uint2* __restrict__ binned, int E, int NB){
  __shared__ int comb[512];
  __shared__ int cur[512];
  int t = threadIdx.x;
  size_t row = (size_t)blockIdx.x * NB;
  if (t < NB) comb[t] = bbase[t] + M[row + t];
  int t2 = t + 256;
  if (t2 < NB) comb[t2] = bbase[t2] + M[row + t2];
  cur[t] = 0; cur[t + 256] = 0;
  __syncthreads();
  int base = blockIdx.x * 4096;
  #pragma unroll 4
  for (int j = t; j < 4096; j += 256){
    int i = base + j;
    if (i < E){
      int d = dst[i];
      int b = d >> 8;
      int r = atomicAdd(&cur[b], 1);
      binned[comb[b] + r] = make_uint2((unsigned)src[i], (unsigned)d);
    }
  }
}

// one block per bucket: row_off + col_idx inside an L2-resident window
__global__ void k_csr(const uint2* __restrict__ binned, const int* __restrict__ bbase,
                      int* __restrict__ row_off, int* __restrict__ col_idx, int n){
  __shared__ int cnt[256];
  __shared__ int off[256];
  __shared__ int cur[256];
  int b = blockIdx.x, t = threadIdx.x;
  int e0 = bbase[b], e1 = bbase[b + 1];
  int nb0 = b << 8;
  cnt[t] = 0; cur[t] = 0;
  __syncthreads();
  int m = e1 - e0;
  for (int j = t; j < m; j += 256) atomicAdd(&cnt[binned[e0 + j].y & 255], 1);
  __syncthreads();
  int v = cnt[t];
  off[t] = v;
  __syncthreads();
  for (int o = 1; o < 256; o <<= 1){
    int u = (t >= o) ? off[t - o] : 0;
    __syncthreads();
    off[t] += u;
    __syncthreads();
  }
  int excl = off[t] - v;
  __syncthreads();
  off[t] = excl;
  if (nb0 + t < n) row_off[nb0 + t] = e0 + excl;
  __syncthreads();
  for (int j = t; j < m; j += 256){
    uint2 p = binned[e0 + j];
    int dl = p.y & 255;
    int r = atomicAdd(&cur[dl], 1);
    col_idx[e0 + off[dl] + r] = (int)p.x;
  }
}

// -------- gather: pooled = sum_{src in N(dst)} h[src] + (1+eps)*h[dst]  (bf16 in/out) --------
__global__ void k_gather(const uint16_t* __restrict__ hb, const int* __restrict__ row_off,
                         const int* __restrict__ col_idx, const float* __restrict__ eps_p,
                         uint16_t* __restrict__ Xb, int n){
  int node = (blockIdx.x << 2) + (threadIdx.x >> 6);
  int lane = threadIdx.x & 63;
  if (node >= n) return;
  const uint32_t* hp = (const uint32_t*)hb;
  uint32_t vh = hp[(size_t)node * 64 + lane];
  int j = row_off[node], jend = row_off[node + 1];
  float a0 = 0.f, a1 = 0.f;
  for (; j + 7 < jend; j += 8){
    int s0 = col_idx[j],     s1 = col_idx[j + 1], s2 = col_idx[j + 2], s3 = col_idx[j + 3];
    int s4 = col_idx[j + 4], s5 = col_idx[j + 5], s6 = col_idx[j + 6], s7 = col_idx[j + 7];
    uint32_t v0 = hp[(size_t)s0 * 64 + lane];
    uint32_t v1 = hp[(size_t)s1 * 64 + lane];
    uint32_t v2 = hp[(size_t)s2 * 64 + lane];
    uint32_t v3 = hp[(size_t)s3 * 64 + lane];
    uint32_t v4 = hp[(size_t)s4 * 64 + lane];
    uint32_t v5 = hp[(size_t)s5 * 64 + lane];
    uint32_t v6 = hp[(size_t)s6 * 64 + lane];
    uint32_t v7 = hp[(size_t)s7 * 64 + lane];
    a0 += ((bflo2f(v0) + bflo2f(v1)) + (bflo2f(v2) + bflo2f(v3)))
        + ((bflo2f(v4) + bflo2f(v5)) + (bflo2f(v6) + bflo2f(v7)));
    a1 += ((bfhi2f(v0) + bfhi2f(v1)) + (bfhi2f(v2) + bfhi2f(v3)))
        + ((bfhi2f(v4) + bfhi2f(v5)) + (bfhi2f(v6) + bfhi2f(v7)));
  }
  for (; j < jend; ++j){
    uint32_t v = hp[(size_t)col_idx[j] * 64 + lane];
    a0 += bflo2f(v);
    a1 += bfhi2f(v);
  }
  float ce = 1.0f + eps_p[0];
  a0 += ce * bflo2f(vh);
  a1 += ce * bfhi2f(vh);
  ((uint32_t*)Xb)[(size_t)node * 64 + lane] = pack2(a0, a1);
}

// -------- MFMA GEMM (as round 3) --------
template<bool BN_IN>
__global__ __launch_bounds__(256, 3) void k_mgemm(
    const uint16_t* __restrict__ Ag, const uint16_t* __restrict__ Wt,
    const float* __restrict__ bias_f, const float* __restrict__ ABin,
    uint16_t* __restrict__ Yout, float* __restrict__ osum, float* __restrict__ osq, int n){
  __shared__ __align__(16) uint16_t Al[64 * 128];
  __shared__ __align__(16) uint16_t Wl[128 * 128];
  __shared__ float csum[128], csq[128];
  int tid = threadIdx.x;
  int rbase = blockIdx.x * 64;

  {
    const uint4* g = (const uint4*)Wt;
    uint4* d = (uint4*)Wl;
    #pragma unroll
    for (int i = 0; i < 8; ++i) d[tid + 256 * i] = g[tid + 256 * i];
  }
  #pragma unroll
  for (int i = 0; i < 4; ++i){
    int f = tid + 256 * i;
    int m = f >> 4, c = f & 15;
    int gr = rbase + m;
    uint4 v = make_uint4(0, 0, 0, 0);
    if (gr < n){
      v = *(const uint4*)(Ag + (size_t)gr * 128 + c * 8);
      if (BN_IN){
        int k0 = c * 8;
        float4 ka0 = *(const float4*)(ABin + k0);
        float4 ka1 = *(const float4*)(ABin + k0 + 4);
        float4 kb0 = *(const float4*)(ABin + 128 + k0);
        float4 kb1 = *(const float4*)(ABin + 128 + k0 + 4);
        float e0 = fmaxf(fmaf(bflo2f(v.x), ka0.x, kb0.x), 0.f);
        float e1 = fmaxf(fmaf(bfhi2f(v.x), ka0.y, kb0.y), 0.f);
        float e2 = fmaxf(fmaf(bflo2f(v.y), ka0.z, kb0.z), 0.f);
        float e3 = fmaxf(fmaf(bfhi2f(v.y), ka0.w, kb0.w), 0.f);
        float e4 = fmaxf(fmaf(bflo2f(v.z), ka1.x, kb1.x), 0.f);
        float e5 = fmaxf(fmaf(bfhi2f(v.z), ka1.y, kb1.y), 0.f);
        float e6 = fmaxf(fmaf(bflo2f(v.w), ka1.z, kb1.z), 0.f);
        float e7 = fmaxf(fmaf(bfhi2f(v.w), ka1.w, kb1.w), 0.f);
        v.x = pack2(e0, e1); v.y = pack2(e2, e3);
        v.z = pack2(e4, e5); v.w = pack2(e6, e7);
      }
    }
    *(uint4*)((char*)Al + m * 256 + ((c ^ (m & 15)) * 16)) = v;
  }
  if (tid < 128){ csum[tid] = 0.f; csq[tid] = 0.f; }
  __syncthreads();

  int lane = tid & 63;
  int w    = tid >> 6;
  int hi   = lane >> 5;
  int key  = lane & 15;
  int m0   = (w & 1) * 32;
  int n0   = (w >> 1) * 64;
  int mrow = m0 + (lane & 31);
  int nrow0 = n0 + (lane & 31);
  int nrow1 = nrow0 + 32;

  f32x16 acc0, acc1;
  #pragma unroll
  for (int i = 0; i < 16; ++i){ acc0[i] = 0.f; acc1[i] = 0.f; }

  const char* Ab = (const char*)Al;
  const char* Wb = (const char*)Wl;
  #pragma unroll
  for (int kt = 0; kt < 8; ++kt){
    int cs = ((2 * kt + hi) ^ key) * 16;
    bf16x8 a  = *(const bf16x8*)(Ab + mrow  * 256 + cs);
    bf16x8 b0 = *(const bf16x8*)(Wb + nrow0 * 256 + cs);
    bf16x8 b1 = *(const bf16x8*)(Wb + nrow1 * 256 + cs);
    acc0 = __builtin_amdgcn_mfma_f32_32x32x16_bf16(a, b0, acc0, 0, 0, 0);
    acc1 = __builtin_amdgcn_mfma_f32_32x32x16_bf16(a, b1, acc1, 0, 0, 0);
  }

  float bias0 = bias_f[nrow0];
  float bias1 = bias_f[nrow1];
  float ps0 = 0.f, pq0 = 0.f, ps1 = 0.f, pq1 = 0.f;
  #pragma unroll
  for (int r = 0; r < 16; ++r){
    int row = (r & 3) + 8 * (r >> 2) + 4 * hi;
    int gr = rbase + m0 + row;
    if (gr < n){
      float y0 = acc0[r] + bias0;
      float y1 = acc1[r] + bias1;
      ps0 += y0; pq0 += y0 * y0;
      ps1 += y1; pq1 += y1 * y1;
      Yout[(size_t)gr * 128 + nrow0] = f2bf(y0);
      Yout[(size_t)gr * 128 + nrow1] = f2bf(y1);
    }
  }
  atomicAdd(&csum[nrow0], ps0); atomicAdd(&csq[nrow0], pq0);
  atomicAdd(&csum[nrow1], ps1); atomicAdd(&csq[nrow1], pq1);
  __syncthreads();
  if (tid < 128){
    atomicAdd(&osum[tid], csum[tid]);
    atomicAdd(&osq[tid], csq[tid]);
  }
}

__global__ void k_bncoef(const float* __restrict__ sum, const float* __restrict__ sq,
                         const float* __restrict__ g, const float* __restrict__ be,
                         float* __restrict__ AB, float invN){
  int c = threadIdx.x;
  if (c < 128){
    float mu = sum[c] * invN;
    float var = sq[c] * invN - mu * mu;
    float A = g[c] * rsqrtf(var + BN_EPS);
    float B = be[c] - mu * A;
    AB[c] = A;
    AB[128 + c] = B;
  }
}

__global__ void k_final(const uint16_t* __restrict__ Y2b, const float* __restrict__ AB,
                        float* __restrict__ out, int total){
  int i = (blockIdx.x * 256 + threadIdx.x) * 4;
  if (i >= total) return;
  uint2 v = *(const uint2*)(Y2b + i);
  int c = i & 127;
  float4 a = *(const float4*)(AB + c);
  float4 b = *(const float4*)(AB + 128 + c);
  float4 o;
  o.x = fmaxf(fmaf(bflo2f(v.x), a.x, b.x), 0.f);
  o.y = fmaxf(fmaf(bfhi2f(v.x), a.y, b.y), 0.f);
  o.z = fmaxf(fmaf(bflo2f(v.y), a.z, b.z), 0.f);
  o.w = fmaxf(fmaf(bfhi2f(v.y), a.w, b.w), 0.f);
  *(float4*)(out + i) = o;
}

extern "C" void kernel_launch(void* const* d_in, const int* in_sizes, int n_in,
                              void* d_out, int out_size, void* d_ws, size_t ws_size,
                              hipStream_t stream){
  const float* h    = (const float*)d_in[0];
  const int*   esrc = (const int*)d_in[1];
  const int*   edst = (const int*)d_in[2];
  const float* W1   = (const float*)d_in[3];
  const float* b1   = (const float*)d_in[4];
  const float* g1   = (const float*)d_in[5];
  const float* be1  = (const float*)d_in[6];
  const float* W2   = (const float*)d_in[7];
  const float* b2   = (const float*)d_in[8];
  const float* g2   = (const float*)d_in[9];
  const float* be2  = (const float*)d_in[10];
  const float* eps  = (const float*)d_in[11];
  int n = in_sizes[0] / 128;
  int E = in_sizes[1];
  (void)n_in; (void)out_size; (void)ws_size;

  int NB = (n + 255) >> 8;       // dst buckets of 256 nodes
  int EB = (E + 4095) >> 12;     // edge blocks of 4096

  char* ws = (char*)d_ws;
  size_t off = 0;
  auto alloc = [&](size_t bytes) -> void* {
    void* p = ws + off;
    off += (bytes + 511) & ~(size_t)511;
    return p;
  };
  size_t feat_b = (size_t)n * 128 * 2;             // bf16 plane 25.6 MB
  uint16_t* B1   = (uint16_t*)alloc(feat_b);        // hb  -> Y1b
  uint16_t* B2   = (uint16_t*)alloc(feat_b);        // binned -> Xb -> Y2b
  int*   row_off = (int*)alloc((size_t)(n + 1) * 4);
  int*   col_idx = (int*)alloc((size_t)E * 4);
  int*   M       = (int*)alloc((size_t)EB * NB * 4);
  int*   btot    = (int*)alloc((size_t)(NB + 1) * 4);
  int*   bbase   = (int*)alloc((size_t)(NB + 1) * 4);
  float* stats   = (float*)alloc(512 * 4);
  float* AB1     = (float*)alloc(256 * 4);
  float* AB2     = (float*)alloc(256 * 4);
  uint16_t* Wt1  = (uint16_t*)alloc(128 * 128 * 2);
  uint16_t* Wt2  = (uint16_t*)alloc(128 * 128 * 2);
  float* sum1 = stats;        float* sq1 = stats + 128;
  float* sum2 = stats + 256;  float* sq2 = stats + 384;
  uint16_t* hb  = B1;
  uint2*   binned = (uint2*)B2;   // dead before Xb is written
  uint16_t* Xb  = B2;
  uint16_t* Y1b = B1;
  uint16_t* Y2b = B2;

  hipMemsetAsync(stats, 0, 512 * 4, stream);

  int total = n * 128;
  k_prep_h<<<(total / 8 + 255) / 256, 256, 0, stream>>>(h, hb, total / 8);
  k_prep_w<<<16, 256, 0, stream>>>(W1, W2, Wt1, Wt2);

  k_bhist  <<<EB, 256, 0, stream>>>(edst, M, E, NB);
  k_colscan<<<NB, 256, 0, stream>>>(M, btot, EB, NB);
  k_bscan  <<<1, 256, 0, stream>>>(btot, bbase, row_off, NB, n, E);
  k_bin    <<<EB, 256, 0, stream>>>(esrc, edst, M, bbase, binned, E, NB);
  k_csr    <<<NB, 256, 0, stream>>>(binned, bbase, row_off, col_idx, n);

  k_gather<<<(n + 3) / 4, 256, 0, stream>>>(hb, row_off, col_idx, eps, Xb, n);

  int gblocks = (n + 63) / 64;
  k_mgemm<false><<<gblocks, 256, 0, stream>>>(Xb, Wt1, b1, nullptr, Y1b, sum1, sq1, n);
  k_bncoef<<<1, 128, 0, stream>>>(sum1, sq1, g1, be1, AB1, 1.0f / (float)n);
  k_mgemm<true> <<<gblocks, 256, 0, stream>>>(Y1b, Wt2, b2, AB1, Y2b, sum2, sq2, n);
  k_bncoef<<<1, 128, 0, stream>>>(sum2, sq2, g2, be2, AB2, 1.0f / (float)n);

  k_final<<<(total / 4 + 255) / 256, 256, 0, stream>>>(Y2b, AB2, (float*)d_out, total);
}

// Round 5
// 360.976 us; speedup vs baseline: 1.7652x; 1.0633x over previous
//
#include <hip/hip_runtime.h>
#include <hip/hip_bf16.h>
#include <stdint.h>

#define BN_EPS 1e-5f

typedef __attribute__((ext_vector_type(8)))  short bf16x8;   // 8 bf16 = 4 VGPRs
typedef __attribute__((ext_vector_type(16))) float f32x16;   // 32x32 MFMA acc

static __device__ __forceinline__ float bflo2f(uint32_t p){
  union { uint32_t u; float f; } c; c.u = p << 16; return c.f;
}
static __device__ __forceinline__ float bfhi2f(uint32_t p){
  union { uint32_t u; float f; } c; c.u = p & 0xffff0000u; return c.f;
}
static __device__ __forceinline__ uint16_t f2bf(float f){
  union { float f; uint32_t u; } c; c.f = f;
  uint32_t u = c.u;
  return (uint16_t)((u + 0x7fffu + ((u >> 16) & 1u)) >> 16);
}
static __device__ __forceinline__ uint32_t pack2(float a, float b){
  return (uint32_t)f2bf(a) | ((uint32_t)f2bf(b) << 16);
}

// ---------------- merged prepass: h fp32->bf16  +  W fp32[k][n] -> Wt bf16[n][k] swizzled ----------------
__global__ void k_prep(const float* __restrict__ h, uint16_t* __restrict__ hb, int hblocks,
                       const float* __restrict__ W1, const float* __restrict__ W2,
                       uint16_t* __restrict__ Wt1, uint16_t* __restrict__ Wt2){
  if ((int)blockIdx.x < hblocks){
    int i = (blockIdx.x * 256 + threadIdx.x) * 8;
    float4 a = *(const float4*)(h + i);
    float4 b = *(const float4*)(h + i + 4);
    uint4 o;
    o.x = pack2(a.x, a.y); o.y = pack2(a.z, a.w);
    o.z = pack2(b.x, b.y); o.w = pack2(b.z, b.w);
    *(uint4*)(hb + i) = o;
    return;
  }
  int gid = (blockIdx.x - hblocks) * 256 + threadIdx.x;   // 4096 chunks total
  if (gid >= 4096) return;
  const float* Wf = (gid < 2048) ? W1 : W2;
  uint16_t* Wt = (gid < 2048) ? Wt1 : Wt2;
  int cid = gid & 2047;
  int nrow = cid >> 4;
  int c    = cid & 15;
  int k0 = c * 8;
  float e[8];
  #pragma unroll
  for (int j = 0; j < 8; ++j) e[j] = Wf[(k0 + j) * 128 + nrow];
  uint4 o;
  o.x = pack2(e[0], e[1]); o.y = pack2(e[2], e[3]);
  o.z = pack2(e[4], e[5]); o.w = pack2(e[6], e[7]);
  int cs = c ^ (nrow & 15);
  *(uint4*)(Wt + nrow * 128 + cs * 8) = o;
}

// ---------------- binned CSR build (no global atomics) ----------------
__global__ void k_bhist(const int* __restrict__ dst, int* __restrict__ M, int E, int NB){
  __shared__ int cnt[512];
  int t = threadIdx.x;
  cnt[t] = 0; cnt[t + 256] = 0;
  __syncthreads();
  int base = blockIdx.x * 4096;
  #pragma unroll 4
  for (int j = t; j < 4096; j += 256){
    int i = base + j;
    if (i < E) atomicAdd(&cnt[dst[i] >> 8], 1);
  }
  __syncthreads();
  size_t row = (size_t)blockIdx.x * NB;
  if (t < NB) M[row + t] = cnt[t];
  int t2 = t + 256;
  if (t2 < NB) M[row + t2] = cnt[t2];
}

__global__ void k_colscan(int* __restrict__ M, int* __restrict__ btot, int EB, int NB){
  __shared__ int s[256];
  int b = blockIdx.x, t = threadIdx.x;
  int i0 = 2 * t, i1 = 2 * t + 1;
  int v0 = (i0 < EB) ? M[(size_t)i0 * NB + b] : 0;
  int v1 = (i1 < EB) ? M[(size_t)i1 * NB + b] : 0;
  s[t] = v0 + v1;
  __syncthreads();
  for (int off = 1; off < 256; off <<= 1){
    int v = (t >= off) ? s[t - off] : 0;
    __syncthreads();
    s[t] += v;
    __syncthreads();
  }
  int excl = s[t] - (v0 + v1);
  if (i0 < EB) M[(size_t)i0 * NB + b] = excl;
  if (i1 < EB) M[(size_t)i1 * NB + b] = excl + v0;
  if (t == 255) btot[b] = s[255];
}

__global__ void k_bscan(const int* __restrict__ btot, int* __restrict__ bbase,
                        int* __restrict__ row_off, int NB, int n, int E){
  __shared__ int s[256];
  int t = threadIdx.x;
  int i0 = 2 * t, i1 = 2 * t + 1;
  int v0 = (i0 < NB) ? btot[i0] : 0;
  int v1 = (i1 < NB) ? btot[i1] : 0;
  s[t] = v0 + v1;
  __syncthreads();
  for (int off = 1; off < 256; off <<= 1){
    int v = (t >= off) ? s[t - off] : 0;
    __syncthreads();
    s[t] += v;
    __syncthreads();
  }
  int excl = s[t] - (v0 + v1);
  if (i0 < NB) bbase[i0] = excl;
  if (i1 < NB) bbase[i1] = excl + v0;
  if (t == 0){ bbase[NB] = E; row_off[n] = E; }
}

__global__ void k_bin(const int* __restrict__ src, const int* __restrict__ dst,
                      const int* __restrict__ M, const int* __restrict__ bbase,
                      uint2* __restrict__ binned, int E, int NB){
  __shared__ int comb[512];
  __shared__ int cur[512];
  int t = threadIdx.x;
  size_t row = (size_t)blockIdx.x * NB;
  if (t < NB) comb[t] = bbase[t] + M[row + t];
  int t2 = t + 256;
  if (t2 < NB) comb[t2] = bbase[t2] + M[row + t2];
  cur[t] = 0; cur[t + 256] = 0;
  __syncthreads();
  int base = blockIdx.x * 4096;
  #pragma unroll 4
  for (int j = t; j < 4096; j += 256){
    int i = base + j;
    if (i < E){
      int d = dst[i];
      int b = d >> 8;
      int r = atomicAdd(&cur[b], 1);
      binned[comb[b] + r] = make_uint2((unsigned)src[i], (unsigned)d);
    }
  }
}

__global__ void k_csr(const uint2* __restrict__ binned, const int* __restrict__ bbase,
                      int* __restrict__ row_off, int* __restrict__ col_idx, int n){
  __shared__ int cnt[256];
  __shared__ int off[256];
  __shared__ int cur[256];
  int b = blockIdx.x, t = threadIdx.x;
  int e0 = bbase[b], e1 = bbase[b + 1];
  int nb0 = b << 8;
  cnt[t] = 0; cur[t] = 0;
  __syncthreads();
  int m = e1 - e0;
  for (int j = t; j < m; j += 256) atomicAdd(&cnt[binned[e0 + j].y & 255], 1);
  __syncthreads();
  int v = cnt[t];
  off[t] = v;
  __syncthreads();
  for (int o = 1; o < 256; o <<= 1){
    int u = (t >= o) ? off[t - o] : 0;
    __syncthreads();
    off[t] += u;
    __syncthreads();
  }
  int excl = off[t] - v;
  __syncthreads();
  off[t] = excl;
  if (nb0 + t < n) row_off[nb0 + t] = e0 + excl;
  __syncthreads();
  for (int j = t; j < m; j += 256){
    uint2 p = binned[e0 + j];
    int dl = p.y & 255;
    int r = atomicAdd(&cur[dl], 1);
    col_idx[e0 + off[dl] + r] = (int)p.x;
  }
}

// -------- gather v2: 16 lanes per row (16B/lane), 4 neighbors per load instruction --------
__global__ void k_gather(const uint16_t* __restrict__ hb, const int* __restrict__ row_off,
                         const int* __restrict__ col_idx, const float* __restrict__ eps_p,
                         uint16_t* __restrict__ Xb, int n){
  int node = (blockIdx.x << 2) + (threadIdx.x >> 6);
  int lane = threadIdx.x & 63;
  if (node >= n) return;
  int g = lane >> 4;        // neighbor slot 0..3
  int c = lane & 15;        // 16-byte chunk within row
  const uint4* hp4 = (const uint4*)hb;   // row stride 16 uint4
  int j = row_off[node], jend = row_off[node + 1];
  float a0=0.f,a1=0.f,a2=0.f,a3=0.f,a4=0.f,a5=0.f,a6=0.f,a7=0.f;
  // 8 neighbors per iteration (2 uint4 loads per lane)
  for (; j + 8 <= jend; j += 8){
    int sA = col_idx[j + g];
    int sB = col_idx[j + 4 + g];
    uint4 vA = hp4[(size_t)sA * 16 + c];
    uint4 vB = hp4[(size_t)sB * 16 + c];
    a0 += bflo2f(vA.x) + bflo2f(vB.x);
    a1 += bfhi2f(vA.x) + bfhi2f(vB.x);
    a2 += bflo2f(vA.y) + bflo2f(vB.y);
    a3 += bfhi2f(vA.y) + bfhi2f(vB.y);
    a4 += bflo2f(vA.z) + bflo2f(vB.z);
    a5 += bfhi2f(vA.z) + bfhi2f(vB.z);
    a6 += bflo2f(vA.w) + bflo2f(vB.w);
    a7 += bfhi2f(vA.w) + bfhi2f(vB.w);
  }
  for (; j + 4 <= jend; j += 4){
    int s = col_idx[j + g];
    uint4 v = hp4[(size_t)s * 16 + c];
    a0 += bflo2f(v.x); a1 += bfhi2f(v.x);
    a2 += bflo2f(v.y); a3 += bfhi2f(v.y);
    a4 += bflo2f(v.z); a5 += bfhi2f(v.z);
    a6 += bflo2f(v.w); a7 += bfhi2f(v.w);
  }
  int rem = jend - j;
  if (rem > 0){
    int jj = j + (g < rem ? g : rem - 1);
    float w = (g < rem) ? 1.f : 0.f;
    int s = col_idx[jj];
    uint4 v = hp4[(size_t)s * 16 + c];
    a0 = fmaf(w, bflo2f(v.x), a0); a1 = fmaf(w, bfhi2f(v.x), a1);
    a2 = fmaf(w, bflo2f(v.y), a2); a3 = fmaf(w, bfhi2f(v.y), a3);
    a4 = fmaf(w, bflo2f(v.z), a4); a5 = fmaf(w, bfhi2f(v.z), a5);
    a6 = fmaf(w, bflo2f(v.w), a6); a7 = fmaf(w, bfhi2f(v.w), a7);
  }
  // fold the 4 neighbor slots (lanes differing in bits 4,5)
  a0 += __shfl_xor(a0, 16); a1 += __shfl_xor(a1, 16);
  a2 += __shfl_xor(a2, 16); a3 += __shfl_xor(a3, 16);
  a4 += __shfl_xor(a4, 16); a5 += __shfl_xor(a5, 16);
  a6 += __shfl_xor(a6, 16); a7 += __shfl_xor(a7, 16);
  a0 += __shfl_xor(a0, 32); a1 += __shfl_xor(a1, 32);
  a2 += __shfl_xor(a2, 32); a3 += __shfl_xor(a3, 32);
  a4 += __shfl_xor(a4, 32); a5 += __shfl_xor(a5, 32);
  a6 += __shfl_xor(a6, 32); a7 += __shfl_xor(a7, 32);
  if (g == 0){
    float ce = 1.0f + eps_p[0];
    uint4 vh = hp4[(size_t)node * 16 + c];
    a0 = fmaf(ce, bflo2f(vh.x), a0); a1 = fmaf(ce, bfhi2f(vh.x), a1);
    a2 = fmaf(ce, bflo2f(vh.y), a2); a3 = fmaf(ce, bfhi2f(vh.y), a3);
    a4 = fmaf(ce, bflo2f(vh.z), a4); a5 = fmaf(ce, bfhi2f(vh.z), a5);
    a6 = fmaf(ce, bflo2f(vh.w), a6); a7 = fmaf(ce, bfhi2f(vh.w), a7);
    uint4 o;
    o.x = pack2(a0, a1); o.y = pack2(a2, a3);
    o.z = pack2(a4, a5); o.w = pack2(a6, a7);
    *((uint4*)Xb + (size_t)node * 16 + c) = o;
  }
}

// -------- MFMA GEMM with LDS-transposed coalesced epilogue --------
template<bool BN_IN>
__global__ __launch_bounds__(256, 3) void k_mgemm(
    const uint16_t* __restrict__ Ag, const uint16_t* __restrict__ Wt,
    const float* __restrict__ bias_f, const float* __restrict__ ABin,
    uint16_t* __restrict__ Yout, float* __restrict__ osum, float* __restrict__ osq, int n){
  __shared__ __align__(16) uint16_t Al[64 * 128];    // 16 KB
  __shared__ __align__(16) uint16_t Wl[128 * 128];   // 32 KB; reused as Y tile (16 KB) in epilogue
  __shared__ float csum[128], csq[128];
  int tid = threadIdx.x;
  int rbase = blockIdx.x * 64;

  {
    const uint4* g = (const uint4*)Wt;
    uint4* d = (uint4*)Wl;
    #pragma unroll
    for (int i = 0; i < 8; ++i) d[tid + 256 * i] = g[tid + 256 * i];
  }
  #pragma unroll
  for (int i = 0; i < 4; ++i){
    int f = tid + 256 * i;
    int m = f >> 4, c = f & 15;
    int gr = rbase + m;
    uint4 v = make_uint4(0, 0, 0, 0);
    if (gr < n){
      v = *(const uint4*)(Ag + (size_t)gr * 128 + c * 8);
      if (BN_IN){
        int k0 = c * 8;
        float4 ka0 = *(const float4*)(ABin + k0);
        float4 ka1 = *(const float4*)(ABin + k0 + 4);
        float4 kb0 = *(const float4*)(ABin + 128 + k0);
        float4 kb1 = *(const float4*)(ABin + 128 + k0 + 4);
        float e0 = fmaxf(fmaf(bflo2f(v.x), ka0.x, kb0.x), 0.f);
        float e1 = fmaxf(fmaf(bfhi2f(v.x), ka0.y, kb0.y), 0.f);
        float e2 = fmaxf(fmaf(bflo2f(v.y), ka0.z, kb0.z), 0.f);
        float e3 = fmaxf(fmaf(bfhi2f(v.y), ka0.w, kb0.w), 0.f);
        float e4 = fmaxf(fmaf(bflo2f(v.z), ka1.x, kb1.x), 0.f);
        float e5 = fmaxf(fmaf(bfhi2f(v.z), ka1.y, kb1.y), 0.f);
        float e6 = fmaxf(fmaf(bflo2f(v.w), ka1.z, kb1.z), 0.f);
        float e7 = fmaxf(fmaf(bfhi2f(v.w), ka1.w, kb1.w), 0.f);
        v.x = pack2(e0, e1); v.y = pack2(e2, e3);
        v.z = pack2(e4, e5); v.w = pack2(e6, e7);
      }
    }
    *(uint4*)((char*)Al + m * 256 + ((c ^ (m & 15)) * 16)) = v;
  }
  if (tid < 128){ csum[tid] = 0.f; csq[tid] = 0.f; }
  __syncthreads();

  int lane = tid & 63;
  int w    = tid >> 6;
  int hi   = lane >> 5;
  int key  = lane & 15;
  int m0   = (w & 1) * 32;
  int n0   = (w >> 1) * 64;
  int mrow = m0 + (lane & 31);
  int nrow0 = n0 + (lane & 31);
  int nrow1 = nrow0 + 32;

  f32x16 acc0, acc1;
  #pragma unroll
  for (int i = 0; i < 16; ++i){ acc0[i] = 0.f; acc1[i] = 0.f; }

  const char* Ab = (const char*)Al;
  const char* Wb = (const char*)Wl;
  #pragma unroll
  for (int kt = 0; kt < 8; ++kt){
    int cs = ((2 * kt + hi) ^ key) * 16;
    bf16x8 a  = *(const bf16x8*)(Ab + mrow  * 256 + cs);
    bf16x8 b0 = *(const bf16x8*)(Wb + nrow0 * 256 + cs);
    bf16x8 b1 = *(const bf16x8*)(Wb + nrow1 * 256 + cs);
    acc0 = __builtin_amdgcn_mfma_f32_32x32x16_bf16(a, b0, acc0, 0, 0, 0);
    acc1 = __builtin_amdgcn_mfma_f32_32x32x16_bf16(a, b1, acc1, 0, 0, 0);
  }
  __syncthreads();   // all waves done reading Wl; safe to reuse as Y tile

  uint16_t* Yl = Wl; // 64 rows x 128 cols bf16 = 16 KB
  float bias0 = bias_f[nrow0];
  float bias1 = bias_f[nrow1];
  float ps0 = 0.f, pq0 = 0.f, ps1 = 0.f, pq1 = 0.f;
  #pragma unroll
  for (int r = 0; r < 16; ++r){
    int row = m0 + (r & 3) + 8 * (r >> 2) + 4 * hi;
    bool valid = (rbase + row) < n;
    float y0 = acc0[r] + bias0;
    float y1 = acc1[r] + bias1;
    if (valid){
      ps0 += y0; pq0 += y0 * y0;
      ps1 += y1; pq1 += y1 * y1;
    }
    Yl[row * 128 + nrow0] = f2bf(y0);
    Yl[row * 128 + nrow1] = f2bf(y1);
  }
  atomicAdd(&csum[nrow0], ps0); atomicAdd(&csq[nrow0], pq0);
  atomicAdd(&csum[nrow1], ps1); atomicAdd(&csq[nrow1], pq1);
  __syncthreads();

  // coalesced store of the 64x128 bf16 tile
  #pragma unroll
  for (int i = 0; i < 4; ++i){
    int id = tid + 256 * i;         // uint4 id, 1024 total
    int row = id >> 4, c = id & 15;
    int gr = rbase + row;
    if (gr < n)
      *((uint4*)Yout + (size_t)gr * 16 + c) = *((const uint4*)Yl + id);
  }
  if (tid < 128){
    atomicAdd(&osum[tid], csum[tid]);
    atomicAdd(&osq[tid], csq[tid]);
  }
}

__global__ void k_bncoef(const float* __restrict__ sum, const float* __restrict__ sq,
                         const float* __restrict__ g, const float* __restrict__ be,
                         float* __restrict__ AB, float invN){
  int c = threadIdx.x;
  if (c < 128){
    float mu = sum[c] * invN;
    float var = sq[c] * invN - mu * mu;
    float A = g[c] * rsqrtf(var + BN_EPS);
    float B = be[c] - mu * A;
    AB[c] = A;
    AB[128 + c] = B;
  }
}

__global__ void k_final(const uint16_t* __restrict__ Y2b, const float* __restrict__ AB,
                        float* __restrict__ out, int total){
  int i = (blockIdx.x * 256 + threadIdx.x) * 4;
  if (i >= total) return;
  uint2 v = *(const uint2*)(Y2b + i);
  int c = i & 127;
  float4 a = *(const float4*)(AB + c);
  float4 b = *(const float4*)(AB + 128 + c);
  float4 o;
  o.x = fmaxf(fmaf(bflo2f(v.x), a.x, b.x), 0.f);
  o.y = fmaxf(fmaf(bfhi2f(v.x), a.y, b.y), 0.f);
  o.z = fmaxf(fmaf(bflo2f(v.y), a.z, b.z), 0.f);
  o.w = fmaxf(fmaf(bfhi2f(v.y), a.w, b.w), 0.f);
  *(float4*)(out + i) = o;
}

extern "C" void kernel_launch(void* const* d_in, const int* in_sizes, int n_in,
                              void* d_out, int out_size, void* d_ws, size_t ws_size,
                              hipStream_t stream){
  const float* h    = (const float*)d_in[0];
  const int*   esrc = (const int*)d_in[1];
  const int*   edst = (const int*)d_in[2];
  const float* W1   = (const float*)d_in[3];
  const float* b1   = (const float*)d_in[4];
  const float* g1   = (const float*)d_in[5];
  const float* be1  = (const float*)d_in[6];
  const float* W2   = (const float*)d_in[7];
  const float* b2   = (const float*)d_in[8];
  const float* g2   = (const float*)d_in[9];
  const float* be2  = (const float*)d_in[10];
  const float* eps  = (const float*)d_in[11];
  int n = in_sizes[0] / 128;
  int E = in_sizes[1];
  (void)n_in; (void)out_size; (void)ws_size;

  int NB = (n + 255) >> 8;
  int EB = (E + 4095) >> 12;

  char* ws = (char*)d_ws;
  size_t off = 0;
  auto alloc = [&](size_t bytes) -> void* {
    void* p = ws + off;
    off += (bytes + 511) & ~(size_t)511;
    return p;
  };
  size_t feat_b = (size_t)n * 128 * 2;
  uint16_t* B1   = (uint16_t*)alloc(feat_b);        // hb  -> Y1b
  uint16_t* B2   = (uint16_t*)alloc(feat_b);        // binned -> Xb -> Y2b
  int*   row_off = (int*)alloc((size_t)(n + 1) * 4);
  int*   col_idx = (int*)alloc((size_t)E * 4);
  int*   M       = (int*)alloc((size_t)EB * NB * 4);
  int*   btot    = (int*)alloc((size_t)(NB + 1) * 4);
  int*   bbase   = (int*)alloc((size_t)(NB + 1) * 4);
  float* stats   = (float*)alloc(512 * 4);
  float* AB1     = (float*)alloc(256 * 4);
  float* AB2     = (float*)alloc(256 * 4);
  uint16_t* Wt1  = (uint16_t*)alloc(128 * 128 * 2);
  uint16_t* Wt2  = (uint16_t*)alloc(128 * 128 * 2);
  float* sum1 = stats;        float* sq1 = stats + 128;
  float* sum2 = stats + 256;  float* sq2 = stats + 384;
  uint16_t* hb  = B1;
  uint2*   binned = (uint2*)B2;
  uint16_t* Xb  = B2;
  uint16_t* Y1b = B1;
  uint16_t* Y2b = B2;

  hipMemsetAsync(stats, 0, 512 * 4, stream);

  int total = n * 128;
  int hblocks = total / 8 / 256;          // 6250 for n=100000
  k_prep<<<hblocks + 16, 256, 0, stream>>>(h, hb, hblocks, W1, W2, Wt1, Wt2);

  k_bhist  <<<EB, 256, 0, stream>>>(edst, M, E, NB);
  k_colscan<<<NB, 256, 0, stream>>>(M, btot, EB, NB);
  k_bscan  <<<1, 256, 0, stream>>>(btot, bbase, row_off, NB, n, E);
  k_bin    <<<EB, 256, 0, stream>>>(esrc, edst, M, bbase, binned, E, NB);
  k_csr    <<<NB, 256, 0, stream>>>(binned, bbase, row_off, col_idx, n);

  k_gather<<<(n + 3) / 4, 256, 0, stream>>>(hb, row_off, col_idx, eps, Xb, n);

  int gblocks = (n + 63) / 64;
  k_mgemm<false><<<gblocks, 256, 0, stream>>>(Xb, Wt1, b1, nullptr, Y1b, sum1, sq1, n);
  k_bncoef<<<1, 128, 0, stream>>>(sum1, sq1, g1, be1, AB1, 1.0f / (float)n);
  k_mgemm<true> <<<gblocks, 256, 0, stream>>>(Y1b, Wt2, b2, AB1, Y2b, sum2, sq2, n);
  k_bncoef<<<1, 128, 0, stream>>>(sum2, sq2, g2, be2, AB2, 1.0f / (float)n);

  k_final<<<(total / 4 + 255) / 256, 256, 0, stream>>>(Y2b, AB2, (float*)d_out, total);
}